// Round 14
// baseline (688.527 us; speedup 1.0000x reference)
//
#include <hip/hip_runtime.h>
#include <stdint.h>

#define N_NODES 100000
#define N_EDGES 1600000
#define IN_DIM 32
#define OUT_DIM 64
#define N_REL 8
#define NSEG (N_NODES * N_REL)         // 800000
#define EPS 1e-10f
#define N_KK 9                          // K-tiles of 32 (8 rel + 1 self)
#define SWG_ELEMS (N_KK * 4 * 64 * 8)   // 18432 bf16 in b-frag order
#define XB_PAIRS (N_NODES * 16)         // 1.6M bf16-pair dwords
#define NTILES ((N_NODES + 63) / 64)    // 1563
#define SEGS_PER_BUCKET 256
#define NBUCK (NSEG / SEGS_PER_BUCKET)  // 3125 exact

typedef __attribute__((ext_vector_type(8))) short bf16x8;
typedef __attribute__((ext_vector_type(4))) float f32x4;

static __device__ __forceinline__ float bflo(uint32_t u) { return __uint_as_float(u << 16); }
static __device__ __forceinline__ float bfhi(uint32_t u) { return __uint_as_float(u & 0xffff0000u); }
static __device__ __forceinline__ uint16_t f2bf(float f) {
    uint32_t u = __float_as_uint(f);
    return (uint16_t)((u + 0x7fffu + ((u >> 16) & 1u)) >> 16); // RNE
}

// ---------------------------------------------------------------------------
// Dtype probe (round-3 proved fp32; kept for robustness, ~3us).
// ---------------------------------------------------------------------------
__global__ __launch_bounds__(256) void detect_kernel(const uint32_t* __restrict__ xw,
                                                     int* __restrict__ flag) {
    __shared__ int cnt;
    if (threadIdx.x == 0) cnt = 0;
    __syncthreads();
    int c = 0;
    for (int k = threadIdx.x; k < 4096; k += 256) {
        uint32_t w = xw[k];
        uint32_t e = (w >> 7) & 0xffu;
        c += (e >= 160u) ? 1 : 0;
    }
    atomicAdd(&cnt, c);
    __syncthreads();
    if (threadIdx.x == 0) *flag = (cnt > 64) ? 1 : 0;  // 1 = fp32 inputs
}

// ---------------------------------------------------------------------------
// prep: (a) xb = x as bf16 pairs; (b) sWg = [Wl;Ws] swizzled to b-frag
// order; (c) biasv = bl+bs.
// ---------------------------------------------------------------------------
__global__ __launch_bounds__(256) void prep_kernel(const void* __restrict__ x,
                                                   const void* __restrict__ Wl,
                                                   const void* __restrict__ Ws,
                                                   const void* __restrict__ bl,
                                                   const void* __restrict__ bs,
                                                   const int* __restrict__ flag,
                                                   uint32_t* __restrict__ xb,
                                                   uint16_t* __restrict__ sWg,
                                                   float* __restrict__ biasv) {
    int f32 = *flag;
    int idx = blockIdx.x * 256 + threadIdx.x;
    if (idx < XB_PAIRS) {
        if (f32) {
            float2 v = ((const float2*)x)[idx];
            xb[idx] = (uint32_t)f2bf(v.x) | ((uint32_t)f2bf(v.y) << 16);
        } else {
            xb[idx] = ((const uint32_t*)x)[idx];
        }
    } else if (idx < XB_PAIRS + SWG_ELEMS) {
        int w = idx - XB_PAIRS;
        int j    = w & 7;
        int lane = (w >> 3) & 63;
        int ot   = (w >> 9) & 3;
        int kk   = w >> 11;
        int quad = lane >> 4;
        int k = kk * 32 + quad * 8 + j;
        int o = ot * 16 + (lane & 15);
        if (f32) {
            float v = (k < 256) ? ((const float*)Wl)[(size_t)k * OUT_DIM + o]
                                : ((const float*)Ws)[(size_t)(k - 256) * OUT_DIM + o];
            sWg[w] = f2bf(v);
        } else {
            sWg[w] = (k < 256) ? ((const uint16_t*)Wl)[(size_t)k * OUT_DIM + o]
                               : ((const uint16_t*)Ws)[(size_t)(k - 256) * OUT_DIM + o];
        }
    } else if (idx < XB_PAIRS + SWG_ELEMS + OUT_DIM) {
        int o = idx - XB_PAIRS - SWG_ELEMS;
        if (f32) biasv[o] = ((const float*)bl)[o] + ((const float*)bs)[o];
        else     biasv[o] = bflo((uint32_t)((const uint16_t*)bl)[o])
                          + bflo((uint32_t)((const uint16_t*)bs)[o]);
    }
}

// ---------------------------------------------------------------------------
// 1) hist: edges per bucket (bucket = seg>>8). 1.6M atomics on 3125 hot,
//    line-batched bins.
// ---------------------------------------------------------------------------
__global__ __launch_bounds__(256) void hist_kernel(const int* __restrict__ el,
                                                   unsigned int* __restrict__ hist) {
    int e = blockIdx.x * 256 + threadIdx.x;
    if (e >= N_EDGES) return;
    int dst = el[e * 3 + 1];
    int rel = el[e * 3 + 2];
    atomicAdd(&hist[(dst * N_REL + rel) >> 8], 1u);
}

// ---------------------------------------------------------------------------
// 2) scan: exclusive scan of hist (3125 vals) in one block; writes bstart
//    (in place over hist, +total at [NBUCK]) and a cursor copy for reorder.
// ---------------------------------------------------------------------------
__global__ __launch_bounds__(256) void scan_kernel(unsigned int* __restrict__ hist,
                                                   unsigned int* __restrict__ cursor) {
    __shared__ unsigned int lds[256];
    const int PER = (NBUCK + 255) / 256;   // 13
    int t = threadIdx.x;
    unsigned int v[13];
    unsigned int loc = 0;
    #pragma unroll
    for (int k = 0; k < PER; ++k) {
        int i = t * PER + k;
        v[k] = (i < NBUCK) ? hist[i] : 0u;
        loc += v[k];
    }
    lds[t] = loc;
    __syncthreads();
    unsigned int xv = lds[t];
    for (int off = 1; off < 256; off <<= 1) {
        unsigned int add = (t >= off) ? lds[t - off] : 0u;
        __syncthreads();
        xv += add;
        lds[t] = xv;
        __syncthreads();
    }
    unsigned int run = (t == 0) ? 0u : lds[t - 1];  // exclusive base
    #pragma unroll
    for (int k = 0; k < PER; ++k) {
        int i = t * PER + k;
        if (i < NBUCK) {
            hist[i] = run;
            cursor[i] = run;
            run += v[k];
        }
    }
    if (t == 255) hist[NBUCK] = lds[255];  // total = N_EDGES
}

// ---------------------------------------------------------------------------
// 3) reorder: epack[pos] = (w_bits<<32) | (src<<8) | seg_local, pos from
//    per-bucket cursor atomics.
// ---------------------------------------------------------------------------
__global__ __launch_bounds__(256) void reorder_kernel(const int* __restrict__ el,
                                                      const void* __restrict__ ew,
                                                      const int* __restrict__ flag,
                                                      unsigned int* __restrict__ cursor,
                                                      uint64_t* __restrict__ epack) {
    int e = blockIdx.x * 256 + threadIdx.x;
    if (e >= N_EDGES) return;
    int src = el[e * 3 + 0];
    int dst = el[e * 3 + 1];
    int rel = el[e * 3 + 2];
    uint32_t wb = (*flag) ? ((const uint32_t*)ew)[e]
                          : (((uint32_t)((const uint16_t*)ew)[e]) << 16);
    int seg = dst * N_REL + rel;
    unsigned int pos = atomicAdd(&cursor[seg >> 8], 1u);
    epack[pos] = ((uint64_t)wb << 32) | ((uint32_t)src << 8) | (uint32_t)(seg & 255);
}

// ---------------------------------------------------------------------------
// 4) aggregate: block = bucket. Accumulate the bucket's 256 segs in LDS
//    (fp32, conflict-free LDS atomics), then divide and flush pre-divided
//    bf16 A to numdiv. NO global atomics, NO global num zeroing.
// ---------------------------------------------------------------------------
__global__ __launch_bounds__(256) void aggregate_kernel(const uint64_t* __restrict__ epack,
                                                        const unsigned int* __restrict__ bstart,
                                                        const uint32_t* __restrict__ xb,
                                                        uint32_t* __restrict__ numdiv) {
    __shared__ float lnum[SEGS_PER_BUCKET * IN_DIM];  // 32KB
    __shared__ float lden[SEGS_PER_BUCKET];           // 1KB

    int b = blockIdx.x;
    for (int k = threadIdx.x; k < SEGS_PER_BUCKET * IN_DIM; k += 256) lnum[k] = 0.f;
    for (int k = threadIdx.x; k < SEGS_PER_BUCKET; k += 256) lden[k] = 0.f;
    __syncthreads();

    unsigned int start = bstart[b];
    unsigned int end   = bstart[b + 1];
    int g    = threadIdx.x >> 5;     // group 0..7 (8 edges per iteration)
    int lane = threadIdx.x & 31;     // feature index

    for (unsigned int e = start + g; e < end; e += 8) {
        uint64_t p = epack[e];               // broadcast across the 32 lanes
        uint32_t lo = (uint32_t)p;
        int seg_local = lo & 255;
        int src = (lo >> 8) & 0x1FFFF;
        float w = __uint_as_float((uint32_t)(p >> 32));
        uint32_t d = xb[(size_t)src * 16 + (lane >> 1)];
        float xv = (lane & 1) ? bfhi(d) : bflo(d);
        atomicAdd(&lnum[seg_local * IN_DIM + lane], w * xv);
        if (lane == 0) atomicAdd(&lden[seg_local], w);
    }
    __syncthreads();

    // flush: numdiv[(b*256+seg_local)*16 + pr] = pack(lnum*inv), coalesced
    for (int idx = threadIdx.x; idx < SEGS_PER_BUCKET * 16; idx += 256) {
        int seg_local = idx >> 4;
        int pr = idx & 15;
        float iv = 1.0f / (lden[seg_local] + EPS);
        float f0 = lnum[seg_local * IN_DIM + 2 * pr] * iv;
        float f1 = lnum[seg_local * IN_DIM + 2 * pr + 1] * iv;
        numdiv[((size_t)b * SEGS_PER_BUCKET + seg_local) * 16 + pr] =
            (uint32_t)f2bf(f0) | ((uint32_t)f2bf(f1) << 16);
    }
}

// ---------------------------------------------------------------------------
// 5) Dense MFMA GEMM (r13 minimal): C = [numdiv | xb] * W + bias, relu.
// b-frags straight from pre-swizzled global sWg; no LDS, no barrier.
// MFMA layouts (HW-verified): A[m=lane&15][k=quad*8+j]; B[k][n=lane&15];
// C row=quad*4+reg, col=lane&15.
// ---------------------------------------------------------------------------
__global__ __launch_bounds__(256) void dense_mfma_kernel(
    const uint16_t* __restrict__ numdiv,   // A[n][256] bf16 row-major
    const uint32_t* __restrict__ xb,
    const uint16_t* __restrict__ sWg,
    const float* __restrict__ biasv,
    const int* __restrict__ flag,
    void* __restrict__ out)
{
    int f32  = *flag;
    int wid  = threadIdx.x >> 6;
    int lane = threadIdx.x & 63;
    int quad = lane >> 4;
    int m    = lane & 15;

    float bias[4];
    #pragma unroll
    for (int ot = 0; ot < 4; ++ot) bias[ot] = biasv[ot * 16 + m];

    int n0 = blockIdx.x * 64 + wid * 16;
    int n  = n0 + m;
    int nc = (n < N_NODES) ? n : (N_NODES - 1);

    f32x4 acc[4];
    #pragma unroll
    for (int ot = 0; ot < 4; ++ot) acc[ot] = (f32x4){0.f, 0.f, 0.f, 0.f};

    #pragma unroll
    for (int kk = 0; kk < N_KK; ++kk) {
        bf16x8 a;
        if (kk < 8) {
            a = *(const bf16x8*)(numdiv + (size_t)nc * 256 + kk * 32 + quad * 8);
        } else {
            a = *(const bf16x8*)((const uint16_t*)xb + (size_t)nc * IN_DIM + quad * 8);
        }
        #pragma unroll
        for (int ot = 0; ot < 4; ++ot) {
            bf16x8 b = *(const bf16x8*)(sWg + ((kk * 4 + ot) * 64 + lane) * 8);
            acc[ot] = __builtin_amdgcn_mfma_f32_16x16x32_bf16(a, b, acc[ot], 0, 0, 0);
        }
    }

    #pragma unroll
    for (int ot = 0; ot < 4; ++ot) {
        #pragma unroll
        for (int reg = 0; reg < 4; ++reg) {
            int node = n0 + quad * 4 + reg;
            if (node >= N_NODES) continue;
            int o = ot * 16 + m;
            float v = fmaxf(acc[ot][reg] + bias[ot], 0.0f);
            if (f32) ((float*)out)[(size_t)node * OUT_DIM + o] = v;
            else     ((uint16_t*)out)[(size_t)node * OUT_DIM + o] = f2bf(v);
        }
    }
}

// ===========================================================================
extern "C" void kernel_launch(void* const* d_in, const int* in_sizes, int n_in,
                              void* d_out, int out_size, void* d_ws, size_t ws_size,
                              hipStream_t stream) {
    const void* x  = d_in[0];
    const int* el  = (const int*)d_in[1];
    const void* ew = d_in[2];
    const void* Wl = d_in[3];
    const void* bl = d_in[4];
    const void* Ws = d_in[5];
    const void* bs = d_in[6];

    // ws: [flag 64B][hist/bstart (NBUCK+1)*4][cursor NBUCK*4][epack 12.8MB]
    //     [numdiv 51.2MB][sWg 36KB][biasv 256B][xb 6.4MB]
    const size_t OFF_HIST = 64;
    const size_t OFF_CUR  = OFF_HIST + (size_t)(NBUCK + 1) * 4;
    const size_t OFF_EPK  = (OFF_CUR + (size_t)NBUCK * 4 + 63) & ~(size_t)63;
    const size_t OFF_NUM  = OFF_EPK + (size_t)N_EDGES * 8;
    const size_t OFF_SWG  = OFF_NUM + (size_t)NSEG * IN_DIM * 2;
    const size_t OFF_BIAS = OFF_SWG + (size_t)SWG_ELEMS * 2;
    const size_t OFF_XB   = OFF_BIAS + OUT_DIM * 4;
    const size_t REQ      = OFF_XB + (size_t)XB_PAIRS * 4;   // ~70.5MB
    if (ws_size < REQ) return; // round-4 evidence: ws >= 105.6MB

    int*          flag   = (int*)d_ws;
    unsigned int* hist   = (unsigned int*)((char*)d_ws + OFF_HIST);
    unsigned int* cursor = (unsigned int*)((char*)d_ws + OFF_CUR);
    uint64_t*     epack  = (uint64_t*)((char*)d_ws + OFF_EPK);
    uint32_t*     numdiv = (uint32_t*)((char*)d_ws + OFF_NUM);
    uint16_t*     sWg    = (uint16_t*)((char*)d_ws + OFF_SWG);
    float*        biasv  = (float*)((char*)d_ws + OFF_BIAS);
    uint32_t*     xb     = (uint32_t*)((char*)d_ws + OFF_XB);

    hipMemsetAsync(d_ws, 0, OFF_EPK, stream);  // flag+hist+cursor (~25KB)
    detect_kernel<<<1, 256, 0, stream>>>((const uint32_t*)x, flag);
    hist_kernel<<<(N_EDGES + 255) / 256, 256, 0, stream>>>(el, hist);
    {
        int total = XB_PAIRS + SWG_ELEMS + OUT_DIM;
        prep_kernel<<<(total + 255) / 256, 256, 0, stream>>>(x, Wl, Ws, bl, bs, flag, xb, sWg, biasv);
    }
    scan_kernel<<<1, 256, 0, stream>>>(hist, cursor);
    reorder_kernel<<<(N_EDGES + 255) / 256, 256, 0, stream>>>(el, ew, flag, cursor, epack);
    aggregate_kernel<<<NBUCK, 256, 0, stream>>>(epack, hist, xb, numdiv);
    dense_mfma_kernel<<<NTILES, 256, 0, stream>>>((const uint16_t*)numdiv, xb, sWg, biasv, flag, d_out);
}